// Round 1
// baseline (201.929 us; speedup 1.0000x reference)
//
#include <hip/hip_runtime.h>

// CrossAttentionAdapter: softmax over a SINGLETON axis => attn == 1 =>
// attn_out[b,p,:] = v[b,:]. Whole Q/K/score path is dead. Output is
// out[b,p,:] = ((x@Wm^T+bm)@Wv^T+bv)@Wo_mha^T+bo_mha)@Wo^T+bo, broadcast over p.
// Chain of 4 GEMMs (M=1024) + 32x row broadcast (268 MB f32 write).

#define BM 64
#define BN 64
#define BK 64

typedef __attribute__((ext_vector_type(8))) __bf16 bf16x8;
typedef __attribute__((ext_vector_type(4))) float f32x4;

__device__ __forceinline__ unsigned short f2bf(float f) {
  unsigned int u = __float_as_uint(f);
  u += 0x7FFFu + ((u >> 16) & 1u);   // RNE
  return (unsigned short)(u >> 16);
}

__global__ void cvt_f32_bf16(const float* __restrict__ x,
                             unsigned short* __restrict__ y, int n4) {
  int i = blockIdx.x * blockDim.x + threadIdx.x;
  if (i >= n4) return;
  const float4 v = reinterpret_cast<const float4*>(x)[i];
  ushort4 o;
  o.x = f2bf(v.x); o.y = f2bf(v.y); o.z = f2bf(v.z); o.w = f2bf(v.w);
  reinterpret_cast<ushort4*>(y)[i] = o;
}

__device__ __forceinline__ void gload_lds16(const void* g, void* l) {
  __builtin_amdgcn_global_load_lds(
      (const __attribute__((address_space(1))) void*)g,
      (__attribute__((address_space(3))) void*)l, 16, 0, 0);
}

// C = A (MxK, bf16 row-major) * W^T (W: NxK bf16 row-major) + bias
// EPI=0: store bf16 activation (ushort), stride N
// EPI=1: store f32, broadcast each row 32x: out[(row*32+p)*N + col]
template <int EPI>
__global__ __launch_bounds__(256, 2) void gemm_bt(
    const unsigned short* __restrict__ A, const unsigned short* __restrict__ W,
    const float* __restrict__ bias, void* __restrict__ outp,
    int M, int N, int K) {
  __shared__ __attribute__((aligned(16))) unsigned short As[BM * BK];
  __shared__ __attribute__((aligned(16))) unsigned short Bs[BN * BK];
  const int tid = threadIdx.x;
  const int lane = tid & 63;
  const int wid = tid >> 6;           // 4 waves: 2x2
  const int wm = wid >> 1;
  const int wn = wid & 1;
  const int bm0 = blockIdx.y * BM;
  const int bn0 = blockIdx.x * BN;

  const int l15 = lane & 15;
  const int l4 = lane >> 4;

  // staging: each 1KB chunk = 8 rows of 64 bf16; wave handles 2 chunks per tile
  const int c0 = wid * 2;
  const int srow = lane >> 3;          // 0..7
  const int scol = (lane & 7) * 8;     // bf16 col (8 elems = 16B per lane)

  f32x4 acc[2][2] = {};

  const size_t Kz = (size_t)K;
  for (int k0 = 0; k0 < K; k0 += BK) {
#pragma unroll
    for (int j = 0; j < 2; ++j) {
      const int c = c0 + j;
      const int r = c * 8 + srow;
      gload_lds16(A + (size_t)(bm0 + r) * Kz + (k0 + scol), &As[c * 512]);
      gload_lds16(W + (size_t)(bn0 + r) * Kz + (k0 + scol), &Bs[c * 512]);
    }
    __syncthreads();   // compiler drains vmcnt(0) before s_barrier
#pragma unroll
    for (int ks = 0; ks < 2; ++ks) {
      const int koff = ks * 32 + l4 * 8;
      bf16x8 a0 = *reinterpret_cast<const bf16x8*>(&As[(wm * 32 + l15) * BK + koff]);
      bf16x8 a1 = *reinterpret_cast<const bf16x8*>(&As[(wm * 32 + 16 + l15) * BK + koff]);
      bf16x8 b0 = *reinterpret_cast<const bf16x8*>(&Bs[(wn * 32 + l15) * BK + koff]);
      bf16x8 b1 = *reinterpret_cast<const bf16x8*>(&Bs[(wn * 32 + 16 + l15) * BK + koff]);
      acc[0][0] = __builtin_amdgcn_mfma_f32_16x16x32_bf16(a0, b0, acc[0][0], 0, 0, 0);
      acc[0][1] = __builtin_amdgcn_mfma_f32_16x16x32_bf16(a0, b1, acc[0][1], 0, 0, 0);
      acc[1][0] = __builtin_amdgcn_mfma_f32_16x16x32_bf16(a1, b0, acc[1][0], 0, 0, 0);
      acc[1][1] = __builtin_amdgcn_mfma_f32_16x16x32_bf16(a1, b1, acc[1][1], 0, 0, 0);
    }
    __syncthreads();
  }

#pragma unroll
  for (int mi = 0; mi < 2; ++mi) {
#pragma unroll
    for (int ni = 0; ni < 2; ++ni) {
      const int col = bn0 + wn * 32 + ni * 16 + l15;
      const float bcol = bias[col];
#pragma unroll
      for (int i = 0; i < 4; ++i) {
        const int row = bm0 + wm * 32 + mi * 16 + l4 * 4 + i;
        const float v = acc[mi][ni][i] + bcol;
        if (EPI == 0) {
          ((unsigned short*)outp)[(size_t)row * N + col] = f2bf(v);
        } else {
          float* o = (float*)outp;
          const size_t base = (size_t)row * 32 * (size_t)N + col;
#pragma unroll
          for (int p = 0; p < 32; ++p) o[base + (size_t)p * N] = v;
        }
      }
    }
  }
}

extern "C" void kernel_launch(void* const* d_in, const int* in_sizes, int n_in,
                              void* d_out, int out_size, void* d_ws, size_t ws_size,
                              hipStream_t stream) {
  const int CLIPd = 1024, Ed = 2048;
  const int Mb = in_sizes[0] / CLIPd;   // 1024

  const float* image = (const float*)d_in[0];
  const float* Wm   = (const float*)d_in[1];
  const float* bm   = (const float*)d_in[2];
  // d_in[3] prefix_queries: dead (softmax over singleton axis)
  const float* Win  = (const float*)d_in[4];
  const float* bin  = (const float*)d_in[5];
  const float* Wo1  = (const float*)d_in[6];
  const float* bo1  = (const float*)d_in[7];
  const float* Wo2  = (const float*)d_in[8];
  const float* bo2  = (const float*)d_in[9];
  float* out = (float*)d_out;

  char* ws = (char*)d_ws;
  const size_t MBy = 1ull << 20;
  unsigned short* Xb   = (unsigned short*)(ws + 0 * MBy);   // 2 MB
  unsigned short* Wmb  = (unsigned short*)(ws + 2 * MBy);   // 4 MB
  unsigned short* Wvb  = (unsigned short*)(ws + 6 * MBy);   // 8 MB
  unsigned short* W1b  = (unsigned short*)(ws + 14 * MBy);  // 8 MB
  unsigned short* W2b  = (unsigned short*)(ws + 22 * MBy);  // 8 MB
  unsigned short* act0 = (unsigned short*)(ws + 30 * MBy);  // 4 MB
  unsigned short* act1 = (unsigned short*)(ws + 34 * MBy);  // 4 MB
  unsigned short* act2 = (unsigned short*)(ws + 38 * MBy);  // 4 MB

  auto cvt = [&](const float* src, unsigned short* dst, long long n) {
    int n4 = (int)(n / 4);
    cvt_f32_bf16<<<(n4 + 255) / 256, 256, 0, stream>>>(src, dst, n4);
  };
  cvt(image, Xb, (long long)Mb * CLIPd);
  cvt(Wm, Wmb, (long long)Ed * CLIPd);
  cvt(Win + (size_t)2 * Ed * Ed, Wvb, (long long)Ed * Ed);  // Wv slice
  cvt(Wo1, W1b, (long long)Ed * Ed);
  cvt(Wo2, W2b, (long long)Ed * Ed);

  dim3 blk(256);
  dim3 g(Ed / BN, Mb / BM);   // (32, 16) = 512 blocks
  gemm_bt<0><<<g, blk, 0, stream>>>(Xb,   Wmb, bm,           act0, Mb, Ed, CLIPd);
  gemm_bt<0><<<g, blk, 0, stream>>>(act0, Wvb, bin + 2 * Ed, act1, Mb, Ed, Ed);
  gemm_bt<0><<<g, blk, 0, stream>>>(act1, W1b, bo1,          act2, Mb, Ed, Ed);
  gemm_bt<1><<<g, blk, 0, stream>>>(act2, W2b, bo2,          out,  Mb, Ed, Ed);
  (void)n_in; (void)out_size; (void)ws_size;
}

// Round 2
// 187.800 us; speedup vs baseline: 1.0752x; 1.0752x over previous
//
#include <hip/hip_runtime.h>

// CrossAttentionAdapter: softmax over a SINGLETON axis => attn == 1 =>
// out[b,p,:] = ((x@Wm^T+bm)@Wv^T+bv)@Wo_mha^T+bo_mha)@Wo^T+bo, independent of p.
// Pipeline: 1 fused f32->bf16 cvt, 4 double-buffered MFMA GEMMs (128x64 tile),
// 1 coalesced x32 broadcast of the final 1024x2048 f32 rows into d_out (268 MB).

#define BM 128
#define BN 64
#define BK 64

typedef __attribute__((ext_vector_type(8))) __bf16 bf16x8;
typedef __attribute__((ext_vector_type(4))) float f32x4;

__device__ __forceinline__ unsigned short f2bf(float f) {
  unsigned int u = __float_as_uint(f);
  u += 0x7FFFu + ((u >> 16) & 1u);   // RNE
  return (unsigned short)(u >> 16);
}

// One fused conversion kernel: 5 f32 source segments -> contiguous bf16 region.
// Segment boundaries in float4 units:
//   image 262144 | Wm 524288 | Wv 1048576 | Wo1 1048576 | Wo2 1048576
__global__ void cvt_all(const float* __restrict__ s0, const float* __restrict__ s1,
                        const float* __restrict__ s2, const float* __restrict__ s3,
                        const float* __restrict__ s4, unsigned short* __restrict__ dst) {
  const size_t NF4 = 3932160;
  size_t i = (size_t)blockIdx.x * blockDim.x + threadIdx.x;
  const size_t stride = (size_t)gridDim.x * blockDim.x;
  for (; i < NF4; i += stride) {
    const float* src; size_t off;
    if (i < 262144)       { src = s0; off = i; }
    else if (i < 786432)  { src = s1; off = i - 262144; }
    else if (i < 1835008) { src = s2; off = i - 786432; }
    else if (i < 2883584) { src = s3; off = i - 1835008; }
    else                  { src = s4; off = i - 2883584; }
    const float4 v = reinterpret_cast<const float4*>(src)[off];
    ushort4 o;
    o.x = f2bf(v.x); o.y = f2bf(v.y); o.z = f2bf(v.z); o.w = f2bf(v.w);
    reinterpret_cast<ushort4*>(dst)[i] = o;
  }
}

__device__ __forceinline__ void gload_lds16(const void* g, void* l) {
  __builtin_amdgcn_global_load_lds(
      (const __attribute__((address_space(1))) void*)g,
      (__attribute__((address_space(3))) void*)l, 16, 0, 0);
}

// C = A (MxK bf16 row-major) * W^T (W: NxK bf16 row-major) + bias
// 2-phase double-buffered: STAGE(next) issued before compute(cur); one
// __syncthreads (vmcnt(0)+lgkmcnt(0) drain) per K-tile => HBM latency hides
// under the MFMA phase. 4 waves, each owns 32 rows x 64 cols (acc[2][4]).
// EPI=0: store bf16 activation. EPI=1: store f32 row-major (no broadcast).
template <int EPI>
__global__ __launch_bounds__(256, 1) void gemm_bt(
    const unsigned short* __restrict__ A, const unsigned short* __restrict__ W,
    const float* __restrict__ bias, void* __restrict__ outp,
    int M, int N, int K) {
  __shared__ __attribute__((aligned(16))) unsigned short As[2][BM * BK];
  __shared__ __attribute__((aligned(16))) unsigned short Bs[2][BN * BK];
  const int tid = threadIdx.x;
  const int lane = tid & 63;
  const int wid = tid >> 6;           // 4 waves, each 32 rows of the 128-row tile
  const int bm0 = blockIdx.y * BM;
  const int bn0 = blockIdx.x * BN;
  const int l15 = lane & 15;
  const int l4 = lane >> 4;
  const int srow = lane >> 3;          // staging: 8 rows x 64 cols per 1KB chunk
  const int scol = (lane & 7) * 8;

  f32x4 acc[2][4] = {};
  const size_t Kz = (size_t)K;

  // As: 16 chunks (4/wave), Bs: 8 chunks (2/wave)
  auto stage = [&](int buf, int k0) {
#pragma unroll
    for (int j = 0; j < 4; ++j) {
      const int c = wid * 4 + j;
      gload_lds16(A + (size_t)(bm0 + c * 8 + srow) * Kz + (k0 + scol),
                  &As[buf][c * 512]);
    }
#pragma unroll
    for (int j = 0; j < 2; ++j) {
      const int c = wid * 2 + j;
      gload_lds16(W + (size_t)(bn0 + c * 8 + srow) * Kz + (k0 + scol),
                  &Bs[buf][c * 512]);
    }
  };

  stage(0, 0);
  __syncthreads();
  const int nt = K / BK;
  int cur = 0;
  for (int t = 0; t < nt; ++t) {
    if (t + 1 < nt) stage(cur ^ 1, (t + 1) * BK);   // prefetch next tile
#pragma unroll
    for (int ks = 0; ks < 2; ++ks) {
      const int koff = ks * 32 + l4 * 8;
      bf16x8 a0 = *reinterpret_cast<const bf16x8*>(&As[cur][(wid * 32 + l15) * BK + koff]);
      bf16x8 a1 = *reinterpret_cast<const bf16x8*>(&As[cur][(wid * 32 + 16 + l15) * BK + koff]);
      bf16x8 b0 = *reinterpret_cast<const bf16x8*>(&Bs[cur][(l15) * BK + koff]);
      bf16x8 b1 = *reinterpret_cast<const bf16x8*>(&Bs[cur][(16 + l15) * BK + koff]);
      bf16x8 b2 = *reinterpret_cast<const bf16x8*>(&Bs[cur][(32 + l15) * BK + koff]);
      bf16x8 b3 = *reinterpret_cast<const bf16x8*>(&Bs[cur][(48 + l15) * BK + koff]);
      acc[0][0] = __builtin_amdgcn_mfma_f32_16x16x32_bf16(a0, b0, acc[0][0], 0, 0, 0);
      acc[0][1] = __builtin_amdgcn_mfma_f32_16x16x32_bf16(a0, b1, acc[0][1], 0, 0, 0);
      acc[0][2] = __builtin_amdgcn_mfma_f32_16x16x32_bf16(a0, b2, acc[0][2], 0, 0, 0);
      acc[0][3] = __builtin_amdgcn_mfma_f32_16x16x32_bf16(a0, b3, acc[0][3], 0, 0, 0);
      acc[1][0] = __builtin_amdgcn_mfma_f32_16x16x32_bf16(a1, b0, acc[1][0], 0, 0, 0);
      acc[1][1] = __builtin_amdgcn_mfma_f32_16x16x32_bf16(a1, b1, acc[1][1], 0, 0, 0);
      acc[1][2] = __builtin_amdgcn_mfma_f32_16x16x32_bf16(a1, b2, acc[1][2], 0, 0, 0);
      acc[1][3] = __builtin_amdgcn_mfma_f32_16x16x32_bf16(a1, b3, acc[1][3], 0, 0, 0);
    }
    __syncthreads();   // drains vmcnt(0) (next tile landed) + lgkmcnt, barrier
    cur ^= 1;
  }

#pragma unroll
  for (int mi = 0; mi < 2; ++mi) {
#pragma unroll
    for (int ni = 0; ni < 4; ++ni) {
      const int col = bn0 + ni * 16 + l15;
      const float bcol = bias[col];
#pragma unroll
      for (int i = 0; i < 4; ++i) {
        const int row = bm0 + wid * 32 + mi * 16 + l4 * 4 + i;
        const float v = acc[mi][ni][i] + bcol;
        if (EPI == 0) {
          ((unsigned short*)outp)[(size_t)row * N + col] = f2bf(v);
        } else {
          ((float*)outp)[(size_t)row * N + col] = v;
        }
      }
    }
  }
}

// out[b,p,:] = rowf[b,:] for p=0..31. Fully coalesced f32x4 nontemporal stores,
// sequential over the 268 MB output; reads hit L2/L3 (8 MB row buffer).
__global__ void bcast_rows(const f32x4* __restrict__ rowf, f32x4* __restrict__ out) {
  const size_t total = (size_t)1024 * 32 * 512;   // output float4 count
  size_t i = (size_t)blockIdx.x * blockDim.x + threadIdx.x;
  const size_t stride = (size_t)gridDim.x * blockDim.x;
  for (; i < total; i += stride) {
    const size_t col4 = i & 511;          // E/4 = 512
    const size_t b = i >> 14;             // / (512*32)
    const f32x4 v = rowf[(b << 9) | col4];
    __builtin_nontemporal_store(v, &out[i]);
  }
}

extern "C" void kernel_launch(void* const* d_in, const int* in_sizes, int n_in,
                              void* d_out, int out_size, void* d_ws, size_t ws_size,
                              hipStream_t stream) {
  const int CLIPd = 1024, Ed = 2048;
  const int Mb = in_sizes[0] / CLIPd;   // 1024

  const float* image = (const float*)d_in[0];
  const float* Wm   = (const float*)d_in[1];
  const float* bm   = (const float*)d_in[2];
  // d_in[3] prefix_queries: dead (softmax over singleton axis)
  const float* Win  = (const float*)d_in[4];
  const float* bin  = (const float*)d_in[5];
  const float* Wo1  = (const float*)d_in[6];
  const float* bo1  = (const float*)d_in[7];
  const float* Wo2  = (const float*)d_in[8];
  const float* bo2  = (const float*)d_in[9];
  float* out = (float*)d_out;

  // ws layout (bf16 elements unless noted): Xb 1M | Wmb 2M | Wvb 4M | W1b 4M |
  // W2b 4M (cvt dst, contiguous, 30 MB) | act0/1/2 2M each | rowf 2M f32 (8 MB)
  unsigned short* wsb = (unsigned short*)d_ws;
  unsigned short* Xb   = wsb;
  unsigned short* Wmb  = wsb + (1u << 20);
  unsigned short* Wvb  = wsb + (3u << 20);
  unsigned short* W1b  = wsb + (7u << 20);
  unsigned short* W2b  = wsb + (11u << 20);
  unsigned short* act0 = wsb + (15u << 20);
  unsigned short* act1 = wsb + (17u << 20);
  unsigned short* act2 = wsb + (19u << 20);
  float* rowf = (float*)(wsb + (21u << 20));

  cvt_all<<<2048, 256, 0, stream>>>(image, Wm, Win + (size_t)2 * Ed * Ed,
                                    Wo1, Wo2, wsb);

  dim3 blk(256);
  dim3 g(Ed / BN, Mb / BM);   // (32, 8) = 256 blocks
  gemm_bt<0><<<g, blk, 0, stream>>>(Xb,   Wmb, bm,           act0, Mb, Ed, CLIPd);
  gemm_bt<0><<<g, blk, 0, stream>>>(act0, Wvb, bin + 2 * Ed, act1, Mb, Ed, Ed);
  gemm_bt<0><<<g, blk, 0, stream>>>(act1, W1b, bo1,          act2, Mb, Ed, Ed);
  gemm_bt<1><<<g, blk, 0, stream>>>(act2, W2b, bo2,          rowf, Mb, Ed, Ed);

  bcast_rows<<<4096, 256, 0, stream>>>((const f32x4*)rowf, (f32x4*)out);
  (void)n_in; (void)out_size; (void)ws_size;
}

// Round 3
// 164.126 us; speedup vs baseline: 1.2303x; 1.1442x over previous
//
#include <hip/hip_runtime.h>

// CrossAttentionAdapter: softmax over a SINGLETON axis => attn == 1 =>
// out[b,p,:] = (((x@Wm^T+bm)@Wv^T+bv)@Wo_mha^T+bo_mha)@Wo^T+bo, independent of p.
// Pipeline: fused f32->bf16 cvt | 4 MFMA GEMMs (128x64 tile, 4-deep LDS ring,
// counted vmcnt, T2 swizzle) | coalesced x32 row-broadcast (268 MB f32 write).

#define BM 128
#define BN 64
#define BK 64
#define NBUF 4

typedef __attribute__((ext_vector_type(8))) __bf16 bf16x8;
typedef __attribute__((ext_vector_type(4))) float f32x4;

__device__ __forceinline__ unsigned short f2bf(float f) {
  unsigned int u = __float_as_uint(f);
  u += 0x7FFFu + ((u >> 16) & 1u);   // RNE
  return (unsigned short)(u >> 16);
}

// One fused conversion kernel: 5 f32 source segments -> contiguous bf16 region.
__global__ void cvt_all(const float* __restrict__ s0, const float* __restrict__ s1,
                        const float* __restrict__ s2, const float* __restrict__ s3,
                        const float* __restrict__ s4, unsigned short* __restrict__ dst) {
  const size_t NF4 = 3932160;   // image 262144 | Wm 524288 | Wv/Wo1/Wo2 1048576 each
  size_t i = (size_t)blockIdx.x * blockDim.x + threadIdx.x;
  const size_t stride = (size_t)gridDim.x * blockDim.x;
  for (; i < NF4; i += stride) {
    const float* src; size_t off;
    if (i < 262144)       { src = s0; off = i; }
    else if (i < 786432)  { src = s1; off = i - 262144; }
    else if (i < 1835008) { src = s2; off = i - 786432; }
    else if (i < 2883584) { src = s3; off = i - 1835008; }
    else                  { src = s4; off = i - 2883584; }
    const float4 v = reinterpret_cast<const float4*>(src)[off];
    ushort4 o;
    o.x = f2bf(v.x); o.y = f2bf(v.y); o.z = f2bf(v.z); o.w = f2bf(v.w);
    reinterpret_cast<ushort4*>(dst)[i] = o;
  }
}

__device__ __forceinline__ void gload_lds16(const void* g, void* l) {
  __builtin_amdgcn_global_load_lds(
      (const __attribute__((address_space(1))) void*)g,
      (__attribute__((address_space(3))) void*)l, 16, 0, 0);
}

// C = A (MxK bf16 row-major) * W^T (W: NxK bf16 row-major) + bias.
// 4-deep ring, counted vmcnt (T3+T4): 3 tiles of global_load_lds always in
// flight; raw s_barrier (no vmcnt(0) drain in main loop). T2 swizzle applied
// as pre-swizzled GLOBAL source column + XOR'd ds_read index (rule #21:
// global_load_lds dest must stay linear). 4 waves, wave tile 64x32, acc[4][2].
// Grid: 256 blocks 1D; bm = bid&7 so each XCD's L2 owns one A row-panel.
template <int EPI>
__global__ __launch_bounds__(256, 1) void gemm_bt(
    const unsigned short* __restrict__ A, const unsigned short* __restrict__ W,
    const float* __restrict__ bias, void* __restrict__ outp,
    int M, int N, int K) {
  __shared__ __attribute__((aligned(16))) unsigned short As[NBUF][BM * BK];
  __shared__ __attribute__((aligned(16))) unsigned short Bs[NBUF][BN * BK];
  const int tid = threadIdx.x;
  const int lane = tid & 63;
  const int wid = tid >> 6;
  const int wm = wid >> 1;        // 0..1: 64-row group
  const int wn = wid & 1;         // 0..1: 32-col group
  const int bid = blockIdx.x;
  const int bm0 = (bid & 7) * BM;   // XCD r <-> A row-panel r
  const int bn0 = (bid >> 3) * BN;
  const int l15 = lane & 15;
  const int l4 = lane >> 4;
  const int lr = lane >> 3;       // row within 8-row staging chunk
  const int lc = lane & 7;
  const int scol = ((lc ^ lr) << 3);  // pre-swizzled source col (elements)

  f32x4 acc[4][2] = {};
  const size_t Kz = (size_t)K;

  // stage one K-tile into ring buffer `buf`: 6 gload_lds per wave
  auto stage = [&](int buf, int tile) {
    const int k0 = tile * BK;
#pragma unroll
    for (int j = 0; j < 4; ++j) {
      const int c = wid * 4 + j;                       // A chunks 0..15
      gload_lds16(A + (size_t)(bm0 + c * 8 + lr) * Kz + (k0 + scol),
                  &As[buf][c * 512]);
    }
#pragma unroll
    for (int j = 0; j < 2; ++j) {
      const int c = wid * 2 + j;                       // B chunks 0..7
      gload_lds16(W + (size_t)(bn0 + c * 8 + lr) * Kz + (k0 + scol),
                  &Bs[buf][c * 512]);
    }
  };

  auto compute = [&](int buf) {
    const int swz = (l15 & 7) << 3;                    // same involution as scol
#pragma unroll
    for (int ks = 0; ks < 2; ++ks) {
      const int kidx = (ks * 32 + l4 * 8) ^ swz;
      bf16x8 a[4], b[2];
#pragma unroll
      for (int mi = 0; mi < 4; ++mi)
        a[mi] = *reinterpret_cast<const bf16x8*>(
            &As[buf][(wm * 64 + mi * 16 + l15) * 64 + kidx]);
#pragma unroll
      for (int ni = 0; ni < 2; ++ni)
        b[ni] = *reinterpret_cast<const bf16x8*>(
            &Bs[buf][(wn * 32 + ni * 16 + l15) * 64 + kidx]);
#pragma unroll
      for (int mi = 0; mi < 4; ++mi)
#pragma unroll
        for (int ni = 0; ni < 2; ++ni)
          acc[mi][ni] = __builtin_amdgcn_mfma_f32_16x16x32_bf16(
              a[mi], b[ni], acc[mi][ni], 0, 0, 0);
    }
  };

  const int nt = K >> 6;            // 16 or 32, always >= 4
  stage(0, 0); stage(1, 1); stage(2, 2);   // 18 outstanding / wave
  int t = 0;
  for (; t < nt - 3; ++t) {
    stage((t + 3) & 3, t + 3);      // 24 outstanding
    asm volatile("s_waitcnt vmcnt(18)" ::: "memory");   // tile t landed
    __builtin_amdgcn_s_barrier();
    compute(t & 3);
    __builtin_amdgcn_s_barrier();   // all waves done reading buf (t&3)
  }
  asm volatile("s_waitcnt vmcnt(12)" ::: "memory");
  __builtin_amdgcn_s_barrier();
  compute(t & 3); ++t;
  __builtin_amdgcn_s_barrier();
  asm volatile("s_waitcnt vmcnt(6)" ::: "memory");
  __builtin_amdgcn_s_barrier();
  compute(t & 3); ++t;
  __builtin_amdgcn_s_barrier();
  asm volatile("s_waitcnt vmcnt(0)" ::: "memory");
  __builtin_amdgcn_s_barrier();
  compute(t & 3);

#pragma unroll
  for (int mi = 0; mi < 4; ++mi)
#pragma unroll
    for (int ni = 0; ni < 2; ++ni) {
      const int col = bn0 + wn * 32 + ni * 16 + l15;
      const float bcol = bias[col];
#pragma unroll
      for (int i = 0; i < 4; ++i) {
        const int row = bm0 + wm * 64 + mi * 16 + l4 * 4 + i;
        const float v = acc[mi][ni][i] + bcol;
        if (EPI == 0) {
          ((unsigned short*)outp)[(size_t)row * N + col] = f2bf(v);
        } else {
          ((float*)outp)[(size_t)row * N + col] = v;
        }
      }
    }
}

// out[b,p,:] = rowf[b,:] for p=0..31. Coalesced f32x4 nontemporal stores.
__global__ void bcast_rows(const f32x4* __restrict__ rowf, f32x4* __restrict__ out) {
  const size_t total = (size_t)1024 * 32 * 512;
  size_t i = (size_t)blockIdx.x * blockDim.x + threadIdx.x;
  const size_t stride = (size_t)gridDim.x * blockDim.x;
  for (; i < total; i += stride) {
    const size_t col4 = i & 511;
    const size_t b = i >> 14;
    const f32x4 v = rowf[(b << 9) | col4];
    __builtin_nontemporal_store(v, &out[i]);
  }
}

extern "C" void kernel_launch(void* const* d_in, const int* in_sizes, int n_in,
                              void* d_out, int out_size, void* d_ws, size_t ws_size,
                              hipStream_t stream) {
  const int CLIPd = 1024, Ed = 2048;
  const int Mb = in_sizes[0] / CLIPd;   // 1024

  const float* image = (const float*)d_in[0];
  const float* bm   = (const float*)d_in[2];
  // d_in[3] prefix_queries: dead (softmax over singleton axis)
  const float* Win  = (const float*)d_in[4];
  const float* bin  = (const float*)d_in[5];
  const float* bo1  = (const float*)d_in[7];
  const float* bo2  = (const float*)d_in[9];
  const float* Wm   = (const float*)d_in[1];
  const float* Wo1  = (const float*)d_in[6];
  const float* Wo2  = (const float*)d_in[8];
  float* out = (float*)d_out;

  unsigned short* wsb = (unsigned short*)d_ws;
  unsigned short* Xb   = wsb;                  // 1M elems
  unsigned short* Wmb  = wsb + (1u << 20);     // 2M
  unsigned short* Wvb  = wsb + (3u << 20);     // 4M
  unsigned short* W1b  = wsb + (7u << 20);     // 4M
  unsigned short* W2b  = wsb + (11u << 20);    // 4M
  unsigned short* act0 = wsb + (15u << 20);    // 2M
  unsigned short* act1 = wsb + (17u << 20);    // 2M
  unsigned short* act2 = wsb + (19u << 20);    // 2M
  float* rowf = (float*)(wsb + (21u << 20));   // 2M f32

  cvt_all<<<2048, 256, 0, stream>>>(image, Wm, Win + (size_t)2 * Ed * Ed,
                                    Wo1, Wo2, wsb);

  gemm_bt<0><<<256, 256, 0, stream>>>(Xb,   Wmb, bm,           act0, Mb, Ed, CLIPd);
  gemm_bt<0><<<256, 256, 0, stream>>>(act0, Wvb, bin + 2 * Ed, act1, Mb, Ed, Ed);
  gemm_bt<0><<<256, 256, 0, stream>>>(act1, W1b, bo1,          act2, Mb, Ed, Ed);
  gemm_bt<1><<<256, 256, 0, stream>>>(act2, W2b, bo2,          rowf, Mb, Ed, Ed);

  bcast_rows<<<4096, 256, 0, stream>>>((const f32x4*)rowf, (f32x4*)out);
  (void)n_in; (void)out_size; (void)ws_size;
}